// Round 1
// baseline (1261.722 us; speedup 1.0000x reference)
//
#include <hip/hip_runtime.h>

// AutoregBlock: B=1024, DIM=384, HID=64, K=8, G=48, MID=128
// Strategy: one block per batch element. Never materialize P (384x384);
// use Pg[g,h] = sum_{l,c} M[g,l,c]*H[h*8+l,c], M[g,l,c] = sum_k w[k,l]*H[g*8+k,c].
// H kept in LDS as bf16 (2% absmax tolerance allows it). FFN weights
// pre-transposed into d_ws for coalesced reads.

#define EPSF 1e-6f

__device__ __forceinline__ unsigned short f2bf(float f) {
    union { float f; unsigned int u; } v; v.f = f;
    unsigned int r = v.u + 0x7fffu + ((v.u >> 16) & 1u);
    return (unsigned short)(r >> 16);
}
__device__ __forceinline__ float bf2f(unsigned short h) {
    union { unsigned int u; float f; } v; v.u = ((unsigned int)h) << 16;
    return v.f;
}
__device__ __forceinline__ float leaky(float v) {
    return v >= 0.0f ? v : 0.01f * v;
}

// ws layout (floats): [0,18432) proj_wT (48x384), [18432,26624) down_wT (64x128),
//                     [26624,34816) up_wT (128x64)
__global__ void transpose_weights(const float* __restrict__ proj_w,
                                  const float* __restrict__ down_w,
                                  const float* __restrict__ up_w,
                                  float* __restrict__ ws) {
    int idx = blockIdx.x * blockDim.x + threadIdx.x;
    if (idx < 18432) {
        int i = idx / 48, g = idx % 48;           // proj_w (384,48) -> (48,384)
        ws[g * 384 + i] = proj_w[idx];
    } else if (idx < 26624) {
        int k = idx - 18432;                      // down_w (128,64) -> (64,128)
        int m = k / 64, c = k % 64;
        ws[18432 + c * 128 + m] = down_w[k];
    } else if (idx < 34816) {
        int k = idx - 26624;                      // up_w (64,128) -> (128,64)
        int cp = k / 128, m = k % 128;
        ws[26624 + m * 64 + cp] = up_w[k];
    }
}

__global__ __launch_bounds__(256) void fused_main(
    const float* __restrict__ x,
    const float* __restrict__ W,
    const float* __restrict__ bb,
    const float* __restrict__ patch_weight,
    const float* __restrict__ pw1, const float* __restrict__ pb1,
    const float* __restrict__ pw2, const float* __restrict__ pb2,
    const float* __restrict__ proj_b,
    const float* __restrict__ down_b,
    const float* __restrict__ up_b,
    const float* __restrict__ ws,
    float* __restrict__ out)
{
    __shared__ unsigned short sH[384 * 64];   // 49152 B  H in bf16, row-major [i][c]
    __shared__ float sA[48 * 65];             // 12480 B  union: M-chunk / Pg / z1-tile
    __shared__ float sw[64];                  // softmaxed patch weight [k][l]
    __shared__ float srw[48];                 // row_weights
    __shared__ float sScale[384];             // per-row scales

    const int t = threadIdx.x;
    const int b = blockIdx.x;
    const float* projT = ws;
    const float* dwT   = ws + 18432;
    const float* uwT   = ws + 26624;

    // ---- P0: softmax over the 64 patch weights (wave 0) ----
    if (t < 64) {
        float p = patch_weight[t];
        float m = p;
        for (int o = 32; o > 0; o >>= 1) m = fmaxf(m, __shfl_xor(m, o));
        float e = expf(p - m);
        float s = e;
        for (int o = 32; o > 0; o >>= 1) s += __shfl_xor(s, o);
        sw[t] = e / s;
    }

    // ---- P1: H = gelu(x*W + (1/(|x|+eps))*b), bf16 into LDS ----
    for (int j = 0; j < 96; ++j) {
        int n = t + 256 * j;              // n = i*64 + c
        int i = n >> 6;
        float xi = x[b * 384 + i];
        float inv = 1.0f / (fabsf(xi) + EPSF);
        float u = xi * W[n] + inv * bb[n];
        float h = 0.5f * u * (1.0f + erff(u * 0.70710678118f));
        sH[n] = f2bf(h);
    }
    __syncthreads();

    // ---- P2/P3: Pg accumulation over 8 c-chunks of width 8 ----
    float acc00=0,acc01=0,acc02=0,acc10=0,acc11=0,acc12=0,acc20=0,acc21=0,acc22=0;
    const int g0 = (t & 15) * 3;          // 16 g-blocks of 3
    const int h0 = (t >> 4) * 3;          // 16 h-blocks of 3

    for (int ch = 0; ch < 8; ++ch) {
        const int c0 = ch * 8;
        // P2: M[g][l][cc] = sum_k w[k][l]*H[g*8+k][c0+cc] -> sA[g*65 + l*8 + cc]
        for (int j = 0; j < 12; ++j) {
            int n = t + 256 * j;          // 0..3071
            int g = n >> 6;
            int rem = n & 63;             // l*8 + cc
            int l = rem >> 3, cc = rem & 7;
            int base = g * 8 * 64 + c0 + cc;
            float s = 0.0f;
            #pragma unroll
            for (int k = 0; k < 8; ++k)
                s += sw[k * 8 + l] * bf2f(sH[base + k * 64]);
            sA[g * 65 + rem] = s;
        }
        __syncthreads();
        // P3: acc[a][e] += sum_{l,cc} M[g0+a,l,cc]*H[(h0+e)*8+l, c0+cc]
        #pragma unroll
        for (int l = 0; l < 8; ++l) {
            #pragma unroll
            for (int cc = 0; cc < 8; ++cc) {
                int mi = l * 8 + cc;
                float m0 = sA[(g0 + 0) * 65 + mi];
                float m1 = sA[(g0 + 1) * 65 + mi];
                float m2 = sA[(g0 + 2) * 65 + mi];
                float v0 = bf2f(sH[((h0 + 0) * 8 + l) * 64 + c0 + cc]);
                float v1 = bf2f(sH[((h0 + 1) * 8 + l) * 64 + c0 + cc]);
                float v2 = bf2f(sH[((h0 + 2) * 8 + l) * 64 + c0 + cc]);
                acc00 += m0 * v0; acc01 += m0 * v1; acc02 += m0 * v2;
                acc10 += m1 * v0; acc11 += m1 * v1; acc12 += m1 * v2;
                acc20 += m2 * v0; acc21 += m2 * v1; acc22 += m2 * v2;
            }
        }
        __syncthreads();
    }

    // ---- P3b: pair ops (elementwise) and store Pg2 into sA[g*48+h] ----
    {
        float a[3][3] = {{acc00,acc01,acc02},{acc10,acc11,acc12},{acc20,acc21,acc22}};
        #pragma unroll
        for (int ia = 0; ia < 3; ++ia) {
            #pragma unroll
            for (int ie = 0; ie < 3; ++ie) {
                int g = g0 + ia, h = h0 + ie;
                int idx = g * 48 + h;
                float v = a[ia][ie];
                v = leaky(v * pw1[idx] + pb1[idx]);
                v = leaky(v * pw2[idx] + pb2[idx]);
                sA[idx] = v;
            }
        }
    }
    __syncthreads();

    // ---- P4: row softmax over h, row_weights = sum 1/(1+p^2) ----
    if (t < 48) {
        const float* row = &sA[t * 48];
        float mx = row[0];
        for (int h = 1; h < 48; ++h) mx = fmaxf(mx, row[h]);
        float s = 0.0f;
        for (int h = 0; h < 48; ++h) s += expf(row[h] - mx);
        float invs = 1.0f / s;
        float rw = 0.0f;
        for (int h = 0; h < 48; ++h) {
            float p = expf(row[h] - mx) * invs;
            rw += 1.0f / (1.0f + p * p);
        }
        srw[t] = rw;
    }
    __syncthreads();

    // ---- P5: scales[i] = rw . proj_w[i,:] + proj_b[i] ----
    for (int i = t; i < 384; i += 256) {
        float s = proj_b[i];
        for (int g = 0; g < 48; ++g) s += srw[g] * projT[g * 384 + i];
        sScale[i] = s;
    }
    __syncthreads();

    // ---- P6: FFN in 16 tiles of 24 rows; z1 tile reuses sA ----
    for (int tile = 0; tile < 16; ++tile) {
        const int r0 = tile * 24;
        // z1[i][m] = leaky(scale[i] * (H[i,:].down_w[m,:]) + down_b[m])
        for (int j = 0; j < 12; ++j) {
            int n = t + 256 * j;          // 0..3071
            int m = n & 127, i = n >> 7;
            int hbase = (r0 + i) * 64;
            float a = 0.0f;
            #pragma unroll 8
            for (int c = 0; c < 64; ++c)
                a += bf2f(sH[hbase + c]) * dwT[c * 128 + m];
            a = a * sScale[r0 + i] + down_b[m];
            sA[i * 128 + m] = leaky(a);
        }
        __syncthreads();
        // z2[i][c'] = leaky(z1[i,:].up_w[c',:] + up_b[c'])
        for (int j = 0; j < 6; ++j) {
            int n = t + 256 * j;          // 0..1535
            int cp = n & 63, i = n >> 6;
            float a = 0.0f;
            #pragma unroll 8
            for (int m = 0; m < 128; ++m)
                a += sA[i * 128 + m] * uwT[m * 64 + cp];
            a = leaky(a + up_b[cp]);
            out[(b * 384 + r0 + i) * 64 + cp] = a;
        }
        __syncthreads();
    }
}

extern "C" void kernel_launch(void* const* d_in, const int* in_sizes, int n_in,
                              void* d_out, int out_size, void* d_ws, size_t ws_size,
                              hipStream_t stream) {
    const float* x      = (const float*)d_in[0];
    const float* W      = (const float*)d_in[1];
    const float* bb     = (const float*)d_in[2];
    const float* pw     = (const float*)d_in[3];
    const float* pw1    = (const float*)d_in[4];
    const float* pb1    = (const float*)d_in[5];
    const float* pw2    = (const float*)d_in[6];
    const float* pb2    = (const float*)d_in[7];
    const float* proj_w = (const float*)d_in[8];
    const float* proj_b = (const float*)d_in[9];
    const float* down_w = (const float*)d_in[10];
    const float* down_b = (const float*)d_in[11];
    const float* up_w   = (const float*)d_in[12];
    const float* up_b   = (const float*)d_in[13];
    float* out = (float*)d_out;
    float* ws  = (float*)d_ws;

    transpose_weights<<<(34816 + 255) / 256, 256, 0, stream>>>(proj_w, down_w, up_w, ws);
    fused_main<<<1024, 256, 0, stream>>>(x, W, bb, pw, pw1, pb1, pw2, pb2,
                                         proj_b, down_b, up_b, ws, out);
}

// Round 2
// 219.978 us; speedup vs baseline: 5.7357x; 5.7357x over previous
//
#include <hip/hip_runtime.h>

// AutoregBlock: B=1024, DIM=384, HID=64, K=8, G=48, MID=128
// One 512-thread block per batch element. MFMA everywhere matmul-shaped:
//   Pg = M(48x512) @ Hg^T   (Hg = H viewed (48,512)),  M[g,l*64+c] = sum_k w[k,l]H[8g+k,c]
//   z1 = (scale*H)(384x64) @ down_w^T(64x128), z2 = z1 @ up_w^T(128x64)
// bf16 LDS tiles with XOR swizzle on 8-elem blocks to kill fragment-load
// bank conflicts. 143 KB LDS, 8 waves, 1 block/CU.

#define EPSF 1e-6f

typedef __attribute__((ext_vector_type(8))) short bf16x8;
typedef __attribute__((ext_vector_type(4))) float f32x4;
typedef __attribute__((ext_vector_type(4))) unsigned short u16x4;

__device__ __forceinline__ unsigned short f2bf(float f) {
    union { float f; unsigned int u; } v; v.f = f;
    unsigned int r = v.u + 0x7fffu + ((v.u >> 16) & 1u);
    return (unsigned short)(r >> 16);
}
__device__ __forceinline__ float bf2f(unsigned short h) {
    union { unsigned int u; float f; } v; v.u = ((unsigned int)h) << 16;
    return v.f;
}
__device__ __forceinline__ float leaky(float v) { return v >= 0.0f ? v : 0.01f * v; }
__device__ __forceinline__ int key8(int r) { return (r ^ (r >> 3)) & 7; }
// gelu tanh-form; safe at |u| huge: exp->inf => tanh->1, exp->0 => tanh->-1
__device__ __forceinline__ float gelu_f(float u) {
    float t  = 0.7978845608028654f * (u + 0.044715f * u * u * u);
    float e  = __expf(2.0f * t);
    float th = 1.0f - 2.0f / (e + 1.0f);
    return 0.5f * u * (1.0f + th);
}

// ws: [0,18432) floats projT (48x384); then bf16: dwB (128x64), uwB (64x128)
__global__ void prep(const float* __restrict__ proj_w,
                     const float* __restrict__ down_w,
                     const float* __restrict__ up_w,
                     float* __restrict__ ws) {
    int idx = blockIdx.x * blockDim.x + threadIdx.x;
    unsigned short* wb = (unsigned short*)(ws + 18432);
    if (idx < 18432) {
        int i = idx / 48, g = idx % 48;
        ws[g * 384 + i] = proj_w[idx];
    } else if (idx < 26624) {
        int k = idx - 18432;
        wb[k] = f2bf(down_w[k]);
    } else if (idx < 34816) {
        int k = idx - 26624;
        wb[8192 + k] = f2bf(up_w[k]);
    }
}

__global__ __launch_bounds__(512, 2) void fused_main(
    const float* __restrict__ x,
    const float* __restrict__ W,
    const float* __restrict__ bb,
    const float* __restrict__ patch_weight,
    const float* __restrict__ pw1, const float* __restrict__ pb1,
    const float* __restrict__ pw2, const float* __restrict__ pb2,
    const float* __restrict__ proj_b,
    const float* __restrict__ down_b,
    const float* __restrict__ up_b,
    const float* __restrict__ ws,
    float* __restrict__ out)
{
    __shared__ __align__(16) unsigned short sH[24576];   // 49152 B (384x64 bf16, swizzled)
    __shared__ __align__(16) unsigned short sM[24576];   // 49152 B (48x512 bf16) / later sDW+sUW
    __shared__ __align__(16) unsigned short sZ1[16384];  // 32768 B (128x128 bf16, swizzled)
    __shared__ float sPg[48 * 49];
    __shared__ float sw[64];
    __shared__ float srw[48];
    __shared__ float sScale[384];
    __shared__ float sDb[128];
    __shared__ float sUb[64];

    const int t = threadIdx.x;
    const int b = blockIdx.x;
    const int wv = t >> 6, lane = t & 63, q = lane >> 4, r = lane & 15;
    const float* projT = ws;
    const unsigned short* dwB = (const unsigned short*)(ws + 18432);
    const unsigned short* uwB = dwB + 8192;
    unsigned short* sDW = sM;          // 128x64 bf16 (8 KBx2) after sM is dead
    unsigned short* sUW = sM + 8192;   // 64x128 bf16

    // ---- P0: softmax of the 64 patch weights (wave 0) ----
    if (t < 64) {
        float p = patch_weight[t];
        float m = p;
        for (int o = 32; o > 0; o >>= 1) m = fmaxf(m, __shfl_xor(m, o));
        float e = __expf(p - m);
        float s = e;
        for (int o = 32; o > 0; o >>= 1) s += __shfl_xor(s, o);
        sw[t] = e / s;
    }

    // ---- P1: H = gelu(x*W + inv*b) -> sH bf16 (swizzled) ----
    for (int j = 0; j < 12; ++j) {
        int idx4 = j * 512 + t;
        int base = idx4 * 4;
        int i = base >> 6, c0 = base & 63;
        float4 w4 = ((const float4*)W)[idx4];
        float4 b4 = ((const float4*)bb)[idx4];
        float xi  = x[b * 384 + i];
        float inv = 1.0f / (fabsf(xi) + EPSF);
        u16x4 hv;
        hv[0] = f2bf(gelu_f(xi * w4.x + inv * b4.x));
        hv[1] = f2bf(gelu_f(xi * w4.y + inv * b4.y));
        hv[2] = f2bf(gelu_f(xi * w4.z + inv * b4.z));
        hv[3] = f2bf(gelu_f(xi * w4.w + inv * b4.w));
        int cb = c0 >> 3, cc = c0 & 7;
        *(u16x4*)&sH[i * 64 + (cb ^ key8(i)) * 8 + cc] = hv;
    }
    __syncthreads();

    // ---- P2: M[g, l*64+c] = sum_k w[k,l]*H[8g+k,c] -> sM bf16 (swizzled) ----
    for (int jj = 0; jj < 6; ++jj) {
        int n = jj * 512 + t;
        int g = n >> 6, rem = n & 63, l = rem >> 3, cb = rem & 7;
        float acc[8];
        #pragma unroll
        for (int z = 0; z < 8; ++z) acc[z] = 0.0f;
        #pragma unroll
        for (int k = 0; k < 8; ++k) {
            int i = g * 8 + k;
            bf16x8 hv = *(const bf16x8*)&sH[i * 64 + (cb ^ key8(i)) * 8];
            float wk = sw[k * 8 + l];
            #pragma unroll
            for (int z = 0; z < 8; ++z) acc[z] += wk * bf2f((unsigned short)hv[z]);
        }
        int cbg = l * 8 + cb;
        int cbs = (cbg & ~7) | ((cbg ^ key8(g)) & 7);
        bf16x8 mv;
        #pragma unroll
        for (int z = 0; z < 8; ++z) mv[z] = (short)f2bf(acc[z]);
        *(bf16x8*)&sM[g * 512 + cbs * 8] = mv;
    }
    __syncthreads();

    // ---- P3: Pg = M @ Hg^T via MFMA; 9 tiles of 16x16, K=512 ----
    for (int tt = wv; tt < 9; tt += 8) {
        int tg = tt / 3, th = tt % 3;
        f32x4 acc = {0.f, 0.f, 0.f, 0.f};
        for (int ks = 0; ks < 16; ++ks) {
            int kf = ks * 32 + q * 8;
            int g = tg * 16 + r;
            int cbg = kf >> 3;
            int cbs = (cbg & ~7) | ((cbg ^ key8(g)) & 7);
            bf16x8 av = *(const bf16x8*)&sM[g * 512 + cbs * 8];
            int h = th * 16 + r;
            int i = h * 8 + (kf >> 6);
            int cbh = (kf & 63) >> 3;
            bf16x8 bv = *(const bf16x8*)&sH[i * 64 + (cbh ^ key8(i)) * 8];
            acc = __builtin_amdgcn_mfma_f32_16x16x32_bf16(av, bv, acc, 0, 0, 0);
        }
        #pragma unroll
        for (int reg = 0; reg < 4; ++reg) {
            int g = tg * 16 + q * 4 + reg;
            int h = th * 16 + r;
            int idx = g * 48 + h;
            float v = acc[reg];
            v = leaky(v * pw1[idx] + pb1[idx]);
            v = leaky(v * pw2[idx] + pb2[idx]);
            sPg[g * 49 + h] = v;
        }
    }
    __syncthreads();

    // ---- P4: row softmax -> row_weights; waves 1..7 stage FFN weights ----
    if (t < 48) {
        const float* row = &sPg[t * 49];
        float mx = row[0];
        for (int h = 1; h < 48; ++h) mx = fmaxf(mx, row[h]);
        float s = 0.0f;
        for (int h = 0; h < 48; ++h) s += __expf(row[h] - mx);
        float invs = 1.0f / s;
        float rw = 0.0f;
        for (int h = 0; h < 48; ++h) {
            float p = __expf(row[h] - mx) * invs;
            rw += 1.0f / (1.0f + p * p);
        }
        srw[t] = rw;
    } else if (t >= 64) {
        for (int cid = t - 64; cid < 2048; cid += 448) {
            if (cid < 1024) {                       // down_w rows (128x64)
                int nrow = cid >> 3, cb = cid & 7;
                bf16x8 v = *(const bf16x8*)&dwB[cid * 8];
                *(bf16x8*)&sDW[nrow * 64 + (cb ^ key8(nrow)) * 8] = v;
            } else {                                // up_w rows (64x128)
                int c2 = cid - 1024;
                int rrow = c2 >> 4, cb = c2 & 15;
                bf16x8 v = *(const bf16x8*)&uwB[c2 * 8];
                int cbs = (cb & 8) | ((cb ^ key8(rrow)) & 7);
                *(bf16x8*)&sUW[rrow * 128 + cbs * 8] = v;
            }
        }
    }
    if (t >= 64 && t < 192)  sDb[t - 64]  = down_b[t - 64];
    if (t >= 192 && t < 256) sUb[t - 192] = up_b[t - 192];
    __syncthreads();

    // ---- P5: scales[i] = srw . projT[:,i] + proj_b[i] ----
    if (t < 384) {
        float s = proj_b[t];
        for (int g = 0; g < 48; ++g) s += srw[g] * projT[g * 384 + t];
        sScale[t] = s;
    }
    __syncthreads();

    // ---- P6: FFN in three 128-row tiles, all-MFMA ----
    for (int rt = 0; rt < 3; ++rt) {
        // z1 = leaky(scale*(H @ dw^T) + db) -> sZ1 bf16
        {
            const int mt = wv;
            f32x4 acc[8];
            #pragma unroll
            for (int nt = 0; nt < 8; ++nt) acc[nt] = (f32x4){0.f, 0.f, 0.f, 0.f};
            #pragma unroll
            for (int ks = 0; ks < 2; ++ks) {
                int i = rt * 128 + mt * 16 + r;
                int cb = ks * 4 + q;
                bf16x8 av = *(const bf16x8*)&sH[i * 64 + (cb ^ key8(i)) * 8];
                #pragma unroll
                for (int nt = 0; nt < 8; ++nt) {
                    int nrow = nt * 16 + r;
                    bf16x8 bv = *(const bf16x8*)&sDW[nrow * 64 + (cb ^ key8(nrow)) * 8];
                    acc[nt] = __builtin_amdgcn_mfma_f32_16x16x32_bf16(av, bv, acc[nt], 0, 0, 0);
                }
            }
            #pragma unroll
            for (int nt = 0; nt < 8; ++nt) {
                #pragma unroll
                for (int reg = 0; reg < 4; ++reg) {
                    int rl = mt * 16 + q * 4 + reg;
                    int i = rt * 128 + rl;
                    int mm = nt * 16 + r;
                    float v = leaky(acc[nt][reg] * sScale[i] + sDb[mm]);
                    int cb = mm >> 3;
                    int cbs = (cb & 8) | ((cb ^ key8(rl)) & 7);
                    sZ1[rl * 128 + cbs * 8 + (mm & 7)] = f2bf(v);
                }
            }
        }
        __syncthreads();
        // z2 = leaky(z1 @ uw^T + ub) -> out
        {
            const int mt = wv;
            f32x4 acc2[4];
            #pragma unroll
            for (int nt = 0; nt < 4; ++nt) acc2[nt] = (f32x4){0.f, 0.f, 0.f, 0.f};
            #pragma unroll
            for (int ks = 0; ks < 4; ++ks) {
                int rl = mt * 16 + r;
                int cb = ks * 4 + q;
                int cbs = (cb & 8) | ((cb ^ key8(rl)) & 7);
                bf16x8 av = *(const bf16x8*)&sZ1[rl * 128 + cbs * 8];
                #pragma unroll
                for (int nt = 0; nt < 4; ++nt) {
                    int nrow = nt * 16 + r;
                    int cbs2 = (cb & 8) | ((cb ^ key8(nrow)) & 7);
                    bf16x8 bv = *(const bf16x8*)&sUW[nrow * 128 + cbs2 * 8];
                    acc2[nt] = __builtin_amdgcn_mfma_f32_16x16x32_bf16(av, bv, acc2[nt], 0, 0, 0);
                }
            }
            #pragma unroll
            for (int nt = 0; nt < 4; ++nt) {
                #pragma unroll
                for (int reg = 0; reg < 4; ++reg) {
                    int i = rt * 128 + mt * 16 + q * 4 + reg;
                    int cp = nt * 16 + r;
                    float v = leaky(acc2[nt][reg] + sUb[cp]);
                    out[(b * 384 + i) * 64 + cp] = v;
                }
            }
        }
        __syncthreads();
    }
}

extern "C" void kernel_launch(void* const* d_in, const int* in_sizes, int n_in,
                              void* d_out, int out_size, void* d_ws, size_t ws_size,
                              hipStream_t stream) {
    const float* x      = (const float*)d_in[0];
    const float* W      = (const float*)d_in[1];
    const float* bb     = (const float*)d_in[2];
    const float* pw     = (const float*)d_in[3];
    const float* pw1    = (const float*)d_in[4];
    const float* pb1    = (const float*)d_in[5];
    const float* pw2    = (const float*)d_in[6];
    const float* pb2    = (const float*)d_in[7];
    const float* proj_w = (const float*)d_in[8];
    const float* proj_b = (const float*)d_in[9];
    const float* down_w = (const float*)d_in[10];
    const float* down_b = (const float*)d_in[11];
    const float* up_w   = (const float*)d_in[12];
    const float* up_b   = (const float*)d_in[13];
    float* out = (float*)d_out;
    float* ws  = (float*)d_ws;

    prep<<<(34816 + 255) / 256, 256, 0, stream>>>(proj_w, down_w, up_w, ws);
    fused_main<<<1024, 512, 0, stream>>>(x, W, bb, pw, pw1, pb1, pw2, pb2,
                                         proj_b, down_b, up_b, ws, out);
}

// Round 3
// 197.591 us; speedup vs baseline: 6.3855x; 1.1133x over previous
//
#include <hip/hip_runtime.h>

// AutoregBlock: B=1024, DIM=384, HID=64, K=8, G=48, MID=128
// One 1024-thread block (16 waves) per batch element, 1 block/CU.
// Pg = M(48x512) @ Hg^T via MFMA (M never larger than 48 KB, P never built).
// FFN z1/z2 via MFMA with 3x2 / 3x1 register supertiles over 192-row passes.
// All bf16 LDS tiles XOR-swizzled on 8-elem blocks.

#define EPSF 1e-6f

typedef __attribute__((ext_vector_type(8))) short bf16x8;
typedef __attribute__((ext_vector_type(4))) float f32x4;
typedef __attribute__((ext_vector_type(4))) unsigned short u16x4;

__device__ __forceinline__ unsigned short f2bf(float f) {
    union { float f; unsigned int u; } v; v.f = f;
    unsigned int r = v.u + 0x7fffu + ((v.u >> 16) & 1u);
    return (unsigned short)(r >> 16);
}
__device__ __forceinline__ float bf2f(unsigned short h) {
    union { unsigned int u; float f; } v; v.u = ((unsigned int)h) << 16;
    return v.f;
}
// leaky(v) = max(v, 0.01v): 2 VALU ops, no divergence
__device__ __forceinline__ float leaky(float v) { return fmaxf(v, 0.01f * v); }
__device__ __forceinline__ int key8(int r) { return (r ^ (r >> 3)) & 7; }
// gelu tanh-form, 8 instr: t = u*(A + B*u^2); e = expf(t); g = u - u*rcp(e+1)
// A = 2*0.7978845608, B = A*0.044715. Saturates correctly at +-inf.
__device__ __forceinline__ float gelu_f(float u) {
    float t = u * (1.5957691216f + 0.0713548163f * (u * u));
    float e = __expf(t);
    float r = __builtin_amdgcn_rcpf(e + 1.0f);
    return fmaf(-u, r, u);
}

// ws: [0,18432) floats projT (48x384); then bf16: dwB (128x64), uwB (64x128)
__global__ void prep(const float* __restrict__ proj_w,
                     const float* __restrict__ down_w,
                     const float* __restrict__ up_w,
                     float* __restrict__ ws) {
    int idx = blockIdx.x * blockDim.x + threadIdx.x;
    unsigned short* wb = (unsigned short*)(ws + 18432);
    if (idx < 18432) {
        int i = idx / 48, g = idx % 48;
        ws[g * 384 + i] = proj_w[idx];
    } else if (idx < 26624) {
        int k = idx - 18432;
        wb[k] = f2bf(down_w[k]);
    } else if (idx < 34816) {
        int k = idx - 26624;
        wb[8192 + k] = f2bf(up_w[k]);
    }
}

__global__ __launch_bounds__(1024, 4) void fused_main(
    const float* __restrict__ x,
    const float* __restrict__ W,
    const float* __restrict__ bb,
    const float* __restrict__ patch_weight,
    const float* __restrict__ pw1, const float* __restrict__ pb1,
    const float* __restrict__ pw2, const float* __restrict__ pb2,
    const float* __restrict__ proj_b,
    const float* __restrict__ down_b,
    const float* __restrict__ up_b,
    const float* __restrict__ ws,
    float* __restrict__ out)
{
    __shared__ __align__(16) unsigned short sH[24576];   // 48 KB H bf16 [i][c] swizzled
    __shared__ __align__(16) unsigned short sRB[24576];  // 48 KB: sM -> {sDW,sUW,sPg}
    __shared__ __align__(16) unsigned short sZ1[24576];  // 48 KB: z1 tile 192x128 bf16
    __shared__ float sw[64];
    __shared__ float srw[48];
    __shared__ float sScale[384];
    __shared__ float sDb[128];
    __shared__ float sUb[64];

    const int t = threadIdx.x;
    const int b = blockIdx.x;
    const int wv = t >> 6, lane = t & 63, q = lane >> 4, r = lane & 15;
    const float* projT = ws;
    const unsigned short* dwB = (const unsigned short*)(ws + 18432);
    const unsigned short* uwB = dwB + 8192;
    unsigned short* sM  = sRB;            // 48x512 bf16 (P2..P3)
    unsigned short* sDW = sRB;            // 128x64 bf16 (P4..)
    unsigned short* sUW = sRB + 8192;     // 64x128 bf16
    float* sPg = (float*)(sRB + 16384);   // 48x49 fp32 (9408 B)

    // ---- P0: softmax of the 64 patch weights (wave 0) ----
    if (t < 64) {
        float p = patch_weight[t];
        float m = p;
        for (int o = 32; o > 0; o >>= 1) m = fmaxf(m, __shfl_xor(m, o));
        float e = __expf(p - m);
        float s = e;
        for (int o = 32; o > 0; o >>= 1) s += __shfl_xor(s, o);
        sw[t] = e * __builtin_amdgcn_rcpf(s);
    }

    // ---- P1: H = gelu(x*W + inv*b) -> sH bf16 (swizzled) ----
    for (int j = 0; j < 6; ++j) {
        int idx4 = j * 1024 + t;
        int base = idx4 * 4;
        int i = base >> 6, c0 = base & 63;
        float4 w4 = ((const float4*)W)[idx4];
        float4 b4 = ((const float4*)bb)[idx4];
        float xi  = x[b * 384 + i];
        float inv = __builtin_amdgcn_rcpf(fabsf(xi) + EPSF);
        u16x4 hv;
        hv[0] = f2bf(gelu_f(fmaf(xi, w4.x, inv * b4.x)));
        hv[1] = f2bf(gelu_f(fmaf(xi, w4.y, inv * b4.y)));
        hv[2] = f2bf(gelu_f(fmaf(xi, w4.z, inv * b4.z)));
        hv[3] = f2bf(gelu_f(fmaf(xi, w4.w, inv * b4.w)));
        int cb = c0 >> 3, cc = c0 & 7;
        *(u16x4*)&sH[i * 64 + ((cb ^ key8(i)) << 3) + cc] = hv;
    }
    __syncthreads();

    // ---- P2: M[g, l*64+c] = sum_k w[k,l]*H[8g+k,c] -> sM bf16 (swizzled) ----
    // Thread owns (g, l-quad, c-block): 1 unpack feeds 4 FMAs.
    if (t < 768) {
        const int cb = t & 7, lq = (t >> 3) & 1, g = t >> 4;
        float acc[4][8];
        #pragma unroll
        for (int a = 0; a < 4; ++a)
            #pragma unroll
            for (int cc = 0; cc < 8; ++cc) acc[a][cc] = 0.0f;
        #pragma unroll
        for (int k = 0; k < 8; ++k) {
            int i = g * 8 + k;
            bf16x8 hv = *(const bf16x8*)&sH[i * 64 + ((cb ^ key8(i)) << 3)];
            f32x4 w4 = *(const f32x4*)&sw[k * 8 + lq * 4];
            float hf[8];
            #pragma unroll
            for (int cc = 0; cc < 8; ++cc) hf[cc] = bf2f((unsigned short)hv[cc]);
            #pragma unroll
            for (int a = 0; a < 4; ++a)
                #pragma unroll
                for (int cc = 0; cc < 8; ++cc) acc[a][cc] = fmaf(w4[a], hf[cc], acc[a][cc]);
        }
        #pragma unroll
        for (int a = 0; a < 4; ++a) {
            int l = lq * 4 + a;
            bf16x8 mv;
            #pragma unroll
            for (int cc = 0; cc < 8; ++cc) mv[cc] = (short)f2bf(acc[a][cc]);
            *(bf16x8*)&sM[g * 512 + ((l * 8 + (cb ^ key8(g))) << 3)] = mv;
        }
    }
    __syncthreads();

    // ---- P3: Pg = M @ Hg^T via MFMA; 9 tiles of 16x16, K=512 (waves 0..8) ----
    f32x4 pacc = {0.f, 0.f, 0.f, 0.f};
    if (wv < 9) {
        const int tg = wv / 3, th = wv % 3;
        for (int ks = 0; ks < 16; ++ks) {
            int kf = ks * 32 + q * 8;
            int g = tg * 16 + r;
            int cbg = kf >> 3;
            int cbs = (cbg & ~7) | ((cbg ^ key8(g)) & 7);
            bf16x8 av = *(const bf16x8*)&sM[g * 512 + (cbs << 3)];
            int h = th * 16 + r;
            int i = h * 8 + (kf >> 6);
            int cbh = (kf & 63) >> 3;
            bf16x8 bv = *(const bf16x8*)&sH[i * 64 + ((cbh ^ key8(i)) << 3)];
            pacc = __builtin_amdgcn_mfma_f32_16x16x32_bf16(av, bv, pacc, 0, 0, 0);
        }
        #pragma unroll
        for (int reg = 0; reg < 4; ++reg) {
            int g = tg * 16 + q * 4 + reg;
            int h = th * 16 + r;
            int idx = g * 48 + h;
            float v = pacc[reg];
            v = leaky(fmaf(v, pw1[idx], pb1[idx]));
            v = leaky(fmaf(v, pw2[idx], pb2[idx]));
            pacc[reg] = v;
        }
    }
    __syncthreads();   // sM dead; region becomes sDW/sUW/sPg

    if (wv < 9) {
        const int tg = wv / 3, th = wv % 3;
        #pragma unroll
        for (int reg = 0; reg < 4; ++reg) {
            int g = tg * 16 + q * 4 + reg;
            int h = th * 16 + r;
            sPg[g * 49 + h] = pacc[reg];
        }
    } else {
        // waves 9..15 stage FFN weights (2048 16B chunks)
        for (int cid = t - 576; cid < 2048; cid += 448) {
            if (cid < 1024) {                       // down_w rows (128x64)
                int nrow = cid >> 3, cb = cid & 7;
                bf16x8 v = *(const bf16x8*)&dwB[cid * 8];
                *(bf16x8*)&sDW[nrow * 64 + ((cb ^ key8(nrow)) << 3)] = v;
            } else {                                // up_w rows (64x128)
                int c2 = cid - 1024;
                int rrow = c2 >> 4, cb = c2 & 15;
                bf16x8 v = *(const bf16x8*)&uwB[c2 * 8];
                int cbs = (cb & 8) | ((cb ^ key8(rrow)) & 7);
                *(bf16x8*)&sUW[rrow * 128 + (cbs << 3)] = v;
            }
        }
    }
    if (t < 128) sDb[t] = down_b[t];
    else if (t < 192) sUb[t - 128] = up_b[t - 128];
    __syncthreads();

    // ---- P4: row softmax -> row_weights, wave-parallel (3 rows/wave) ----
    {
        #pragma unroll
        for (int rr = 0; rr < 3; ++rr) {
            int row = wv + rr * 16;
            float v = (lane < 48) ? sPg[row * 49 + lane] : -1e30f;
            float m = v;
            for (int o = 32; o > 0; o >>= 1) m = fmaxf(m, __shfl_xor(m, o));
            float e = (lane < 48) ? __expf(v - m) : 0.0f;
            float s = e;
            for (int o = 32; o > 0; o >>= 1) s += __shfl_xor(s, o);
            float p = e * __builtin_amdgcn_rcpf(s);
            float rwv = (lane < 48) ? __builtin_amdgcn_rcpf(fmaf(p, p, 1.0f)) : 0.0f;
            for (int o = 32; o > 0; o >>= 1) rwv += __shfl_xor(rwv, o);
            if (lane == 0) srw[row] = rwv;
        }
    }
    __syncthreads();

    // ---- P5: scales[i] = srw . projT[:,i] + proj_b[i] ----
    if (t < 384) {
        float s = proj_b[t];
        #pragma unroll 4
        for (int g = 0; g < 48; ++g) s = fmaf(srw[g], projT[g * 384 + t], s);
        sScale[t] = s;
    }
    __syncthreads();

    // ---- P6: FFN in two 192-row passes, register-supertiled MFMA ----
    const int mg = wv >> 2, ng = wv & 3;
    for (int rt = 0; rt < 2; ++rt) {
        const int r0 = rt * 192;
        // z1 = leaky(scale*(H @ dw^T) + db) -> sZ1 bf16 ; supertile 3m x 2n
        {
            f32x4 zacc[3][2];
            #pragma unroll
            for (int a = 0; a < 3; ++a)
                #pragma unroll
                for (int e = 0; e < 2; ++e) zacc[a][e] = (f32x4){0.f, 0.f, 0.f, 0.f};
            #pragma unroll
            for (int ks = 0; ks < 2; ++ks) {
                int cb = ks * 4 + q;
                bf16x8 af[3];
                #pragma unroll
                for (int a = 0; a < 3; ++a) {
                    int i = r0 + (mg * 3 + a) * 16 + r;
                    af[a] = *(const bf16x8*)&sH[i * 64 + ((cb ^ key8(i)) << 3)];
                }
                #pragma unroll
                for (int e = 0; e < 2; ++e) {
                    int n = (ng * 2 + e) * 16 + r;
                    bf16x8 bv = *(const bf16x8*)&sDW[n * 64 + ((cb ^ key8(n)) << 3)];
                    #pragma unroll
                    for (int a = 0; a < 3; ++a)
                        zacc[a][e] = __builtin_amdgcn_mfma_f32_16x16x32_bf16(af[a], bv, zacc[a][e], 0, 0, 0);
                }
            }
            #pragma unroll
            for (int a = 0; a < 3; ++a) {
                #pragma unroll
                for (int e = 0; e < 2; ++e) {
                    #pragma unroll
                    for (int reg = 0; reg < 4; ++reg) {
                        int rl = (mg * 3 + a) * 16 + q * 4 + reg;
                        int m = (ng * 2 + e) * 16 + r;
                        float v = leaky(fmaf(zacc[a][e][reg], sScale[r0 + rl], sDb[m]));
                        int cb2 = m >> 3;
                        int cbs2 = (cb2 & 8) | ((cb2 ^ key8(rl)) & 7);
                        sZ1[rl * 128 + (cbs2 << 3) + (m & 7)] = f2bf(v);
                    }
                }
            }
        }
        __syncthreads();
        // z2 = leaky(z1 @ uw^T + ub) -> out ; supertile 3m x 1n
        {
            f32x4 oacc[3];
            #pragma unroll
            for (int a = 0; a < 3; ++a) oacc[a] = (f32x4){0.f, 0.f, 0.f, 0.f};
            #pragma unroll
            for (int ks = 0; ks < 4; ++ks) {
                int cb = ks * 4 + q;
                int cp = ng * 16 + r;
                int cbsB = (cb & 8) | ((cb ^ key8(cp)) & 7);
                bf16x8 bv = *(const bf16x8*)&sUW[cp * 128 + (cbsB << 3)];
                #pragma unroll
                for (int a = 0; a < 3; ++a) {
                    int rl = (mg * 3 + a) * 16 + r;
                    int cbsA = (cb & 8) | ((cb ^ key8(rl)) & 7);
                    bf16x8 av = *(const bf16x8*)&sZ1[rl * 128 + (cbsA << 3)];
                    oacc[a] = __builtin_amdgcn_mfma_f32_16x16x32_bf16(av, bv, oacc[a], 0, 0, 0);
                }
            }
            #pragma unroll
            for (int a = 0; a < 3; ++a) {
                #pragma unroll
                for (int reg = 0; reg < 4; ++reg) {
                    int i = r0 + (mg * 3 + a) * 16 + q * 4 + reg;
                    int cp = ng * 16 + r;
                    out[(b * 384 + i) * 64 + cp] = leaky(oacc[a][reg] + sUb[cp]);
                }
            }
        }
        __syncthreads();
    }
}

extern "C" void kernel_launch(void* const* d_in, const int* in_sizes, int n_in,
                              void* d_out, int out_size, void* d_ws, size_t ws_size,
                              hipStream_t stream) {
    const float* x      = (const float*)d_in[0];
    const float* W      = (const float*)d_in[1];
    const float* bb     = (const float*)d_in[2];
    const float* pw     = (const float*)d_in[3];
    const float* pw1    = (const float*)d_in[4];
    const float* pb1    = (const float*)d_in[5];
    const float* pw2    = (const float*)d_in[6];
    const float* pb2    = (const float*)d_in[7];
    const float* proj_w = (const float*)d_in[8];
    const float* proj_b = (const float*)d_in[9];
    const float* down_w = (const float*)d_in[10];
    const float* down_b = (const float*)d_in[11];
    const float* up_w   = (const float*)d_in[12];
    const float* up_b   = (const float*)d_in[13];
    float* out = (float*)d_out;
    float* ws  = (float*)d_ws;

    prep<<<(34816 + 255) / 256, 256, 0, stream>>>(proj_w, down_w, up_w, ws);
    fused_main<<<1024, 1024, 0, stream>>>(x, W, bb, pw, pw1, pb1, pw2, pb2,
                                          proj_b, down_b, up_b, ws, out);
}